// Round 8
// baseline (366.071 us; speedup 1.0000x reference)
//
#include <hip/hip_runtime.h>

// LocallyConnected2D: y[n,h,w] = relu(sum_{i,j} x[n,h+i,w+j]*W[h,w,i,j] + b[h,w])
// lane = batch n (N=64=wave). History:
//  R1: scalar (SMEM) weights -> lgkmcnt drains mixed with ds_read.
//  R2: f[12] local array -> scratch (223MB writes).
//  R3: VMEM uniform weights + full unroll -> hoist pressure -> spill.
//  R4: weights via LDS broadcast (full unroll) -> hoisted ds_reads, spill.
//  R5: manual cur/nxt prefetch + memory clobber -> arrays in scratch (1.78GB).
//  R6: sched_barrier(0x7) regions -> allocator catastrophe (3.68GB scratch).
//  R7: runtime r loop, weights as per-iter uniform VMEM loads. 284us.
//  R8: weights bulk-staged to LDS, 18 broadcast ds_read_b128/iter. 205us.
//  R9: weights global->VGPR pack, readlane+fma hot loop, XOR-swizzled x LDS,
//      H_T=4, 3 blocks/CU (12 waves). 172us.
//  R10/R11: register-array prefetch -> SPILLED (357us). Never again.
//  R12: global_load_lds DMA row-ring -> 274us (memory system idle). Dumb
//      wide staging burst wins.
//  R13: H_T=8, 512-thr, 16 waves/CU. 176us: FETCH -58MB, time FLAT.
//  R14: H_T=12, 768-thr, 24 waves/CU (+50% TLP). 187us: occupancy 51%,
//      time FLAT AGAIN. Traffic, occupancy, tile shape all varied; time
//      pinned 172-187us, VALUBusy pinned 52-56%. The invariant is the
//      hot loop: 1 v_readlane per v_fmac (20.6M each), interleaved ->
//      VALU->SGPR->VALU hazard padding + nothing to fill the gaps.
//  R15 (this): broadcast moves to the SCALAR pipe. Weights are wave-uniform;
//      read them through a provably-uniform pointer so the compiler emits
//      s_load_dword (scalar cache, co-issues with VALU) and v_fmac v,s,v.
//      Inner loop: 72 s_load + 4 ds_read_b128 + one lgkm drain + 72 fmac.
//      Zero cross-lane ops, zero readlane hazard. Frame identical to R14.
//      Clean A/B: flat result would falsify the readlane theory and point
//      at batch-major global scatter instead.

#define H_IN 512
#define W_IN 512
#define H_OUT 504
#define W_OUT 504
#define W_T 8
#define H_T 12
#define TROWS (H_T + 8)       // 20 staged input rows
#define XF (TROWS * 1024)     // 20480 floats = 80 KB -> 2 blocks/CU (160KB exact)
#define NTX 63                // tiles in w
#define NTY 42                // tiles in h (504/12)
#define NBLK (NTX * NTY)      // 2646

__launch_bounds__(768, 6)
__global__ void lc2d_kernel(const float* __restrict__ x,
                            const float* __restrict__ weight,
                            const float* __restrict__ bias,
                            float* __restrict__ out) {
    __shared__ float lds[XF];   // x tile: [row][wq][ (n*4)^(wq*4) ] swizzled

    const int t    = threadIdx.x;
    const int lane = t & 63;          // batch index n (compute phase)
    const int wv   = t >> 6;          // wave 0..11

    // bijective XCD swizzle: consecutive swz (= ty-adjacent tiles sharing
    // 8 x-rows) map to the same XCD, concurrently -> L2 reuse.
    int swz;
    {
        const int bid = blockIdx.x;
        const int xcd = bid & 7, i = bid >> 3;
        const int q = NBLK >> 3, r = NBLK & 7;          // 330, 6
        swz = (xcd < r ? xcd * (q + 1)
                       : r * (q + 1) + (xcd - r) * q) + i;
    }
    const int ty = swz % NTY;
    const int tx = swz / NTY;
    const int h0 = ty * H_T;
    const int w0 = tx * W_T;

    // ---- stage x tile; thread t: wq = t&3, n = (t>>2)&63, rg = t>>8 (0..2)
    // rows rg, rg+3, ..., rg+18 (7 reps, mask row>=20). Coalesced 64B per
    // 4 threads. LDS float addr = row*1024 + wq*256 + (n*4 ^ wq*4).
    {
        const int wq = t & 3;
        const int n  = (t >> 2) & 63;
        const int rg = t >> 8;
        const float* gx = x + (size_t)n * (H_IN * W_IN)
                            + (size_t)h0 * W_IN + w0 + wq * 4;
        float* ld = &lds[wq * 256 + ((n * 4) ^ (wq * 4))];
        #pragma unroll
        for (int rep = 0; rep < 7; ++rep) {
            const int row = rg + rep * 3;
            if (row < TROWS) {
                const float4 v =
                    *reinterpret_cast<const float4*>(gx + (size_t)row * W_IN);
                *reinterpret_cast<float4*>(ld + row * 1024) = v;
            }
        }
    }

    __syncthreads();

    const int wvu = __builtin_amdgcn_readfirstlane(wv);
    const int h   = h0 + wvu;         // this wave's output row (uniform)

    // wave-uniform weight base: every operand below is uniform (readfirstlane
    // + blockIdx) with compile-time indices -> compiler emits s_load_dword,
    // consumed as the SGPR operand of v_fmac. No readlane, no LDS.
    const float* __restrict__ wb = weight + ((size_t)h * W_OUT + w0) * 81;

    float acc[W_T];
    {
        const float* bptr = bias + (size_t)h * W_OUT + w0;   // uniform: s_load
        #pragma unroll
        for (int k = 0; k < W_T; ++k) acc[k] = bptr[k];
    }

    // 4 swizzled x chunk pointers for this lane; row offset advances 1024/iter
    const float* xp0 = &lds[0 * 256 + ((lane * 4) ^ 0)  + wvu * 1024];
    const float* xp1 = &lds[1 * 256 + ((lane * 4) ^ 4)  + wvu * 1024];
    const float* xp2 = &lds[2 * 256 + ((lane * 4) ^ 8)  + wvu * 1024];
    const float* xp3 = &lds[3 * 256 + ((lane * 4) ^ 12) + wvu * 1024];

    #pragma unroll 1
    for (int r = 0; r < 9; ++r) {
        // x row (wvu + r): 16 floats/lane via 4 conflict-free ds_read_b128
        float xr[16];
        {
            const float4 v0 = *reinterpret_cast<const float4*>(xp0);
            const float4 v1 = *reinterpret_cast<const float4*>(xp1);
            const float4 v2 = *reinterpret_cast<const float4*>(xp2);
            const float4 v3 = *reinterpret_cast<const float4*>(xp3);
            xr[0]  = v0.x; xr[1]  = v0.y; xr[2]  = v0.z; xr[3]  = v0.w;
            xr[4]  = v1.x; xr[5]  = v1.y; xr[6]  = v1.z; xr[7]  = v1.w;
            xr[8]  = v2.x; xr[9]  = v2.y; xr[10] = v2.z; xr[11] = v2.w;
            xr[12] = v3.x; xr[13] = v3.y; xr[14] = v3.z; xr[15] = v3.w;
        }

        const int r9 = r * 9;     // uniform (SALU)

        // 72 scalar weight loads + 72 v_fmac (SGPR weight operand).
        // tp outer / k inner: consecutive fmacs hit different acc chains.
        #pragma unroll
        for (int tp = 0; tp < 9; ++tp) {
            #pragma unroll
            for (int k = 0; k < W_T; ++k) {
                const float w = wb[k * 81 + r9 + tp];   // uniform -> s_load
                acc[k] = fmaf(w, xr[k + tp], acc[k]);
            }
        }

        xp0 += 1024; xp1 += 1024; xp2 += 1024; xp3 += 1024;
    }

    // ---- epilogue: ReLU + regular stores (L2 write-combines; nt amplified
    // scattered writes 1.7x in R12) ----
    float* o = out + (size_t)lane * (H_OUT * W_OUT) + (size_t)h * W_OUT + w0;
    float4 s;
    s.x = fmaxf(acc[0], 0.f); s.y = fmaxf(acc[1], 0.f);
    s.z = fmaxf(acc[2], 0.f); s.w = fmaxf(acc[3], 0.f);
    *reinterpret_cast<float4*>(o) = s;
    s.x = fmaxf(acc[4], 0.f); s.y = fmaxf(acc[5], 0.f);
    s.z = fmaxf(acc[6], 0.f); s.w = fmaxf(acc[7], 0.f);
    *reinterpret_cast<float4*>(o + 4) = s;
}

extern "C" void kernel_launch(void* const* d_in, const int* in_sizes, int n_in,
                              void* d_out, int out_size, void* d_ws, size_t ws_size,
                              hipStream_t stream) {
    const float* x      = (const float*)d_in[0];
    const float* weight = (const float*)d_in[1];
    const float* bias   = (const float*)d_in[2];
    float* out          = (float*)d_out;

    dim3 grid(NBLK);
    dim3 block(768);
    lc2d_kernel<<<grid, block, 0, stream>>>(x, weight, bias, out);
}

// Round 9
// 308.949 us; speedup vs baseline: 1.1849x; 1.1849x over previous
//
#include <hip/hip_runtime.h>

// LocallyConnected2D: y[n,h,w] = relu(sum_{i,j} x[n,h+i,w+j]*W[h,w,i,j] + b[h,w])
// lane = batch n (N=64=wave). History:
//  R1..R8: see git log. Highlights: R2/R3/R5/R6 = spill disasters from
//      unrolled/fenced shapes; R7 VMEM-uniform weights 284us; R8 LDS
//      broadcast weights 205us (LDS-pipe-bound).
//  R9: weights global->VGPR pack, readlane+fma hot loop, XOR-swizzled x LDS,
//      H_T=4, 3 blocks/CU. 172us. BEST of the one-shot-tile family.
//  R10/R11: register-array prefetch (66 held regs) -> SPILLED, 357us.
//  R12: global_load_lds DMA row-ring -> 274us (memory system idle; DMA
//      scatter-issue + vmcnt(0)/tile serialization).
//  R13: H_T=8, 16 waves/CU: FETCH -58MB, time FLAT (176us).
//  R14: H_T=12, 24 waves/CU: occupancy 51%, time FLAT (187us).
//  R15: weights via s_load (scalar pipe): VALUBusy 53->10.6%, time UP 244us.
//      A/B conclusion: real VALU issue is only ~21%; K$ path worse than
//      readlane. Also: R9 did 335MB @1.95TB/s while R13 did 278MB @1.58 ->
//      NOT at a bandwidth cap either. The 172-187us floor = per-tile COLD
//      START (weight gather + full x restage serial before compute) times
//      #generations, unhidden.
//  R16 (this): remove the cold start; keep R9 compute core byte-identical.
//      - 63 cols x 8 segs = 504 blocks, ALL co-resident (2/CU, 64KB):
//        no generation turnover; adjacent columns concurrent -> L2 absorbs
//        the 8-float w-halo.
//      - 16-slot LDS row ring (slot = h&15): consecutive tiles in a column
//        share 8/12 rows -> steady state stages only 4 rows (16KB)/tile.
//      - 1-tile-ahead prefetch in 34 held VGPRs (rxa..rxd float4 + wnx[18]):
//        issue at top of compute, vmcnt-drain + ds_write + barrier at
//        bottom, wpk<-wnx copy. (R14 proved wpk[18] across compute = no
//        spill @ VGPR 40; R10's spill was 66 regs + lambda soup.)
//      Spill alarm: WRITE_SIZE > 80MB -> revert held-reg prefetch.

#define H_IN 512
#define W_IN 512
#define H_OUT 504
#define W_OUT 504
#define W_T 8
#define H_T 4
#define NTX 63                // w columns
#define NTYT 126              // h-tiles per column
#define NSEG 8                // segments per column
#define NBLK (NSEG * NTX)     // 504 blocks -> all co-resident
#define RS 16                 // ring slots (rows)
#define XF (RS * 1024)        // 16384 floats = 64 KB -> 2 blocks/CU

__device__ __forceinline__ float readlane_f(float v, int l) {
    return __int_as_float(__builtin_amdgcn_readlane(__float_as_int(v), l));
}

__launch_bounds__(256, 2)
__global__ void lc2d_kernel(const float* __restrict__ x,
                            const float* __restrict__ weight,
                            const float* __restrict__ bias,
                            float* __restrict__ out) {
    __shared__ float lds[XF];   // x row ring: [h&15][wq][ (n*4)^(wq*4) ]

    const int t    = threadIdx.x;
    const int lane = t & 63;          // batch index n (compute phase)
    const int wv   = t >> 6;          // wave 0..3
    const int wvu  = __builtin_amdgcn_readfirstlane(wv);

    // bid = seg*NTX + col: col fastest -> adjacent columns co-resident
    const int col = blockIdx.x % NTX;
    const int seg = blockIdx.x / NTX;
    const int ty0 = (seg * NTYT) / NSEG;         // first h-tile
    const int ty1 = ((seg + 1) * NTYT) / NSEG;   // one past last
    const int w0  = col * W_T;

    // staging mapping: thread t = (n = t>>2, wq = t&3); 1 float4 per row
    const int sn   = t >> 2;
    const int swq  = t & 3;
    const int sof  = swq * 256 + ((sn * 4) ^ (swq * 4));   // swizzled slot off
    const float* gxb = x + (size_t)sn * (H_IN * W_IN) + w0 + swq * 4;

    // weight pack mapping: p = q*16 + rr, q = k*9+tp (0..71), rr = tap row
    const int qb = lane >> 4;     // 0..3
    const int rr = lane & 15;

    // ---- prologue: stage rows 4*ty0 .. +11 into ring; load first wpk ----
    {
        const int hb = ty0 * H_T;
        #pragma unroll
        for (int rrow = 0; rrow < 12; ++rrow) {
            const int hrow = hb + rrow;
            const float4 v = *reinterpret_cast<const float4*>(
                gxb + (size_t)hrow * W_IN);
            *reinterpret_cast<float4*>(&lds[(hrow & 15) * 1024 + sof]) = v;
        }
    }
    float wpk[18];
    {
        const float* wb = weight + ((size_t)(ty0 * H_T + wv) * W_OUT + w0) * 81;
        #pragma unroll
        for (int d = 0; d < 18; ++d) {
            const int q  = 4 * d + qb;        // 0..71
            const int k  = q / 9;             // magic-mul
            const int tp = q - 9 * k;
            float v = 0.f;
            if (rr < 9) v = __builtin_nontemporal_load(wb + k * 81 + rr * 9 + tp);
            wpk[d] = v;
        }
    }
    __syncthreads();

    // lane's 4 swizzled chunk offsets within a row slot (constant)
    const int lo0 = 0 * 256 + ((lane * 4) ^ 0);
    const int lo1 = 1 * 256 + ((lane * 4) ^ 4);
    const int lo2 = 2 * 256 + ((lane * 4) ^ 8);
    const int lo3 = 3 * 256 + ((lane * 4) ^ 12);

    for (int ty = ty0; ty < ty1; ++ty) {
        const int h0   = ty * H_T;
        const bool more = (ty + 1 < ty1);

        // ---- prefetch next tile: 4 x rows + weights, into held regs ----
        float4 rxa, rxb, rxc, rxd;
        if (more) {
            rxa = *reinterpret_cast<const float4*>(gxb + (size_t)(h0 + 12) * W_IN);
            rxb = *reinterpret_cast<const float4*>(gxb + (size_t)(h0 + 13) * W_IN);
            rxc = *reinterpret_cast<const float4*>(gxb + (size_t)(h0 + 14) * W_IN);
            rxd = *reinterpret_cast<const float4*>(gxb + (size_t)(h0 + 15) * W_IN);
        }
        float wnx[18];
        if (more) {
            const float* wb = weight + ((size_t)(h0 + 4 + wv) * W_OUT + w0) * 81;
            #pragma unroll
            for (int d = 0; d < 18; ++d) {
                const int q  = 4 * d + qb;
                const int k  = q / 9;
                const int tp = q - 9 * k;
                float v = 0.f;
                if (rr < 9)
                    v = __builtin_nontemporal_load(wb + k * 81 + rr * 9 + tp);
                wnx[d] = v;
            }
        }

        // ---- compute current tile from ring + wpk (R9 core) ----
        const int h  = h0 + wvu;                 // this wave's output row
        const int hb = h;                        // uniform ring base row

        float acc[W_T];
        {
            const float* bptr = bias + (size_t)h * W_OUT + w0;  // uniform s_load
            #pragma unroll
            for (int k = 0; k < W_T; ++k) acc[k] = bptr[k];
        }

        #pragma unroll 1
        for (int r = 0; r < 9; ++r) {
            const int sl = ((hb + r) & 15) * 1024;   // uniform SALU

            float xr[16];
            {
                const float4 v0 = *reinterpret_cast<const float4*>(&lds[sl + lo0]);
                const float4 v1 = *reinterpret_cast<const float4*>(&lds[sl + lo1]);
                const float4 v2 = *reinterpret_cast<const float4*>(&lds[sl + lo2]);
                const float4 v3 = *reinterpret_cast<const float4*>(&lds[sl + lo3]);
                xr[0]  = v0.x; xr[1]  = v0.y; xr[2]  = v0.z; xr[3]  = v0.w;
                xr[4]  = v1.x; xr[5]  = v1.y; xr[6]  = v1.z; xr[7]  = v1.w;
                xr[8]  = v2.x; xr[9]  = v2.y; xr[10] = v2.z; xr[11] = v2.w;
                xr[12] = v3.x; xr[13] = v3.y; xr[14] = v3.z; xr[15] = v3.w;
            }

            const int li0 = r;
            const int li1 = r + 16;
            const int li2 = r + 32;
            const int li3 = r + 48;

            #pragma unroll
            for (int tp = 0; tp < 9; ++tp) {
                #pragma unroll
                for (int k = 0; k < W_T; ++k) {
                    const int q  = k * 9 + tp;          // compile-time
                    const int qm = q & 3;
                    const int li = (qm == 0) ? li0 : (qm == 1) ? li1
                                 : (qm == 2) ? li2 : li3;
                    const float w = readlane_f(wpk[q >> 2], li);
                    acc[k] = fmaf(w, xr[k + tp], acc[k]);
                }
            }
        }

        // ---- epilogue: ReLU + regular stores ----
        {
            float* o = out + (size_t)lane * (H_OUT * W_OUT)
                           + (size_t)h * W_OUT + w0;
            float4 s;
            s.x = fmaxf(acc[0], 0.f); s.y = fmaxf(acc[1], 0.f);
            s.z = fmaxf(acc[2], 0.f); s.w = fmaxf(acc[3], 0.f);
            *reinterpret_cast<float4*>(o) = s;
            s.x = fmaxf(acc[4], 0.f); s.y = fmaxf(acc[5], 0.f);
            s.z = fmaxf(acc[6], 0.f); s.w = fmaxf(acc[7], 0.f);
            *reinterpret_cast<float4*>(o + 4) = s;
        }

        // ---- land prefetched rows into ring slots 12..15 (disjoint from
        // the 12 slots this tile's compute read), then barrier ----
        if (more) {
            *reinterpret_cast<float4*>(&lds[((h0 + 12) & 15) * 1024 + sof]) = rxa;
            *reinterpret_cast<float4*>(&lds[((h0 + 13) & 15) * 1024 + sof]) = rxb;
            *reinterpret_cast<float4*>(&lds[((h0 + 14) & 15) * 1024 + sof]) = rxc;
            *reinterpret_cast<float4*>(&lds[((h0 + 15) & 15) * 1024 + sof]) = rxd;
        }
        __syncthreads();
        if (more) {
            #pragma unroll
            for (int d = 0; d < 18; ++d) wpk[d] = wnx[d];
        }
    }
}

extern "C" void kernel_launch(void* const* d_in, const int* in_sizes, int n_in,
                              void* d_out, int out_size, void* d_ws, size_t ws_size,
                              hipStream_t stream) {
    const float* x      = (const float*)d_in[0];
    const float* weight = (const float*)d_in[1];
    const float* bias   = (const float*)d_in[2];
    float* out          = (float*)d_out;

    dim3 grid(NBLK);
    dim3 block(256);
    lc2d_kernel<<<grid, block, 0, stream>>>(x, weight, bias, out);
}